// Round 1
// baseline (363.532 us; speedup 1.0000x reference)
//
#include <hip/hip_runtime.h>

#define D 64
#define ED 32
#define NN 50000
#define EE 800000

// broadcast value from lane `l` (compile-time const after unroll) -> SGPR
__device__ __forceinline__ float rl(float v, int l) {
    return __int_as_float(__builtin_amdgcn_readlane(__float_as_int(v), l));
}

// Node kernel A: kx = x@Wk[:D] + bk ; qx = x@Wq[:D] + bq
__global__ void node_kq(const float* __restrict__ x,
                        const float* __restrict__ Wk, const float* __restrict__ bk,
                        const float* __restrict__ Wq, const float* __restrict__ bq,
                        float* __restrict__ kx, float* __restrict__ qx, int nWaves) {
    const int lane = threadIdx.x & 63;
    const int wid  = blockIdx.x * 4 + (threadIdx.x >> 6);
    float wk[D], wq[D];
#pragma unroll
    for (int c = 0; c < D; ++c) {
        wk[c] = Wk[c * D + lane];
        wq[c] = Wq[c * D + lane];
    }
    const float bkv = bk[lane], bqv = bq[lane];
    for (int n = wid; n < NN; n += nWaves) {
        const float xv = x[(size_t)n * D + lane];
        float aK = bkv, aQ = bqv;
#pragma unroll
        for (int c = 0; c < D; ++c) {
            const float a = rl(xv, c);
            aK = fmaf(a, wk[c], aK);
            aQ = fmaf(a, wq[c], aQ);
        }
        kx[(size_t)n * D + lane] = aK;
        qx[(size_t)n * D + lane] = aQ;
    }
}

// Node kernel B: vx = x@Wv[:D] + bv ; out = x@Wskip + bias  (initializes out)
__global__ void node_vs(const float* __restrict__ x,
                        const float* __restrict__ Wv, const float* __restrict__ bv,
                        const float* __restrict__ Ws, const float* __restrict__ bias,
                        float* __restrict__ vx, float* __restrict__ out, int nWaves) {
    const int lane = threadIdx.x & 63;
    const int wid  = blockIdx.x * 4 + (threadIdx.x >> 6);
    float wv[D], ws[D];
#pragma unroll
    for (int c = 0; c < D; ++c) {
        wv[c] = Wv[c * D + lane];
        ws[c] = Ws[c * D + lane];
    }
    const float bvv = bv[lane], bsv = bias[lane];
    for (int n = wid; n < NN; n += nWaves) {
        const float xv = x[(size_t)n * D + lane];
        float aV = bvv, aS = bsv;
#pragma unroll
        for (int c = 0; c < D; ++c) {
            const float a = rl(xv, c);
            aV = fmaf(a, wv[c], aV);
            aS = fmaf(a, ws[c], aS);
        }
        vx[(size_t)n * D + lane]  = aV;
        out[(size_t)n * D + lane] = aS;
    }
}

// Edge kernel: one wave per edge (grid-stride).
// msg = sigmoid((kx[dst]+ea@WkE) + (qx[src]+ea@WqE)) * (vx[src]+ea@WvE)
// out[dst] += msg  (atomic)
__global__ void edge_kernel(const int* __restrict__ srcI, const int* __restrict__ dstI,
                            const float* __restrict__ ea,
                            const float* __restrict__ Wk, const float* __restrict__ Wq,
                            const float* __restrict__ Wv,
                            const float* __restrict__ kx, const float* __restrict__ qx,
                            const float* __restrict__ vx,
                            float* __restrict__ out, int nWaves) {
    const int lane = threadIdx.x & 63;
    const int wid  = blockIdx.x * 4 + (threadIdx.x >> 6);
    float wkE[ED], wqE[ED], wvE[ED];
#pragma unroll
    for (int c = 0; c < ED; ++c) {
        wkE[c] = Wk[(D + c) * D + lane];   // rows D..D+ED-1 = edge part
        wqE[c] = Wq[(D + c) * D + lane];
        wvE[c] = Wv[(D + c) * D + lane];
    }
    for (int e = wid; e < EE; e += nWaves) {
        const int eu = __builtin_amdgcn_readfirstlane(e);   // wave-uniform -> s_load path
        const int s  = srcI[eu];
        const int dd = dstI[eu];
        const float eav = ea[(size_t)eu * ED + (lane & 31)];  // coalesced, 2-way bcast
        float aK = 0.f, aQ = 0.f, aV = 0.f;
#pragma unroll
        for (int c = 0; c < ED; ++c) {
            const float a = rl(eav, c);
            aK = fmaf(a, wkE[c], aK);
            aQ = fmaf(a, wqE[c], aQ);
            aV = fmaf(a, wvE[c], aV);
        }
        const float k = kx[(size_t)dd * D + lane] + aK;
        const float q = qx[(size_t)s  * D + lane] + aQ;
        const float v = vx[(size_t)s  * D + lane] + aV;
        const float z = k + q;
        const float g = 1.0f / (1.0f + __expf(-z));
        unsafeAtomicAdd(&out[(size_t)dd * D + lane], g * v);
    }
}

extern "C" void kernel_launch(void* const* d_in, const int* in_sizes, int n_in,
                              void* d_out, int out_size, void* d_ws, size_t ws_size,
                              hipStream_t stream) {
    const float* x    = (const float*)d_in[0];
    const int*   eidx = (const int*)d_in[1];      // [2, E]: row0=src, row1=dst
    const float* eatt = (const float*)d_in[2];
    const float* Wk   = (const float*)d_in[3];
    const float* bk   = (const float*)d_in[4];
    const float* Wq   = (const float*)d_in[5];
    const float* bq   = (const float*)d_in[6];
    const float* Wv   = (const float*)d_in[7];
    const float* bv   = (const float*)d_in[8];
    const float* Ws   = (const float*)d_in[9];
    const float* bias = (const float*)d_in[10];
    float* out = (float*)d_out;

    float* kx = (float*)d_ws;                       // [N, D]
    float* qx = kx + (size_t)NN * D;                // [N, D]
    float* vx = qx + (size_t)NN * D;                // [N, D]

    const int* srcI = eidx;
    const int* dstI = eidx + EE;

    // Node kernels: 512 blocks x 256 thr = 2048 waves
    const int nodeBlocks = 512;
    const int nodeWaves  = nodeBlocks * 4;
    node_kq<<<nodeBlocks, 256, 0, stream>>>(x, Wk, bk, Wq, bq, kx, qx, nodeWaves);
    node_vs<<<nodeBlocks, 256, 0, stream>>>(x, Wv, bv, Ws, bias, vx, out, nodeWaves);

    // Edge kernel: 2048 blocks x 256 thr = 8192 waves, ~98 edges/wave
    const int edgeBlocks = 2048;
    const int edgeWaves  = edgeBlocks * 4;
    edge_kernel<<<edgeBlocks, 256, 0, stream>>>(srcI, dstI, eatt, Wk, Wq, Wv,
                                                kx, qx, vx, out, edgeWaves);
}

// Round 2
// 286.237 us; speedup vs baseline: 1.2700x; 1.2700x over previous
//
#include <hip/hip_runtime.h>

#define D 64
#define ED 32
#define NN 50000
#define EE 800000

// broadcast value from lane `l` (compile-time const after unroll) -> SGPR
__device__ __forceinline__ float rl(float v, int l) {
    return __int_as_float(__builtin_amdgcn_readlane(__float_as_int(v), l));
}

// Node kernel A: kx = x@Wk[:D] + bk ; qx = x@Wq[:D] + bq
__global__ __launch_bounds__(256, 3)
void node_kq(const float* __restrict__ x,
             const float* __restrict__ Wk, const float* __restrict__ bk,
             const float* __restrict__ Wq, const float* __restrict__ bq,
             float* __restrict__ kx, float* __restrict__ qx, int nWaves) {
    const int lane = threadIdx.x & 63;
    const int wid  = blockIdx.x * 4 + (threadIdx.x >> 6);
    float wk[D], wq[D];
#pragma unroll
    for (int c = 0; c < D; ++c) {
        wk[c] = Wk[c * D + lane];
        wq[c] = Wq[c * D + lane];
    }
    const float bkv = bk[lane], bqv = bq[lane];
    for (int n = wid; n < NN; n += nWaves) {
        const float xv = x[(size_t)n * D + lane];
        float aK = bkv, aQ = bqv;
#pragma unroll
        for (int c = 0; c < D; ++c) {
            const float a = rl(xv, c);
            aK = fmaf(a, wk[c], aK);
            aQ = fmaf(a, wq[c], aQ);
        }
        kx[(size_t)n * D + lane] = aK;
        qx[(size_t)n * D + lane] = aQ;
    }
}

// Node kernel B: vx = x@Wv[:D] + bv ; out = x@Wskip + bias  (initializes out)
__global__ __launch_bounds__(256, 3)
void node_vs(const float* __restrict__ x,
             const float* __restrict__ Wv, const float* __restrict__ bv,
             const float* __restrict__ Ws, const float* __restrict__ bias,
             float* __restrict__ vx, float* __restrict__ out, int nWaves) {
    const int lane = threadIdx.x & 63;
    const int wid  = blockIdx.x * 4 + (threadIdx.x >> 6);
    float wv[D], ws[D];
#pragma unroll
    for (int c = 0; c < D; ++c) {
        wv[c] = Wv[c * D + lane];
        ws[c] = Ws[c * D + lane];
    }
    const float bvv = bv[lane], bsv = bias[lane];
    for (int n = wid; n < NN; n += nWaves) {
        const float xv = x[(size_t)n * D + lane];
        float aV = bvv, aS = bsv;
#pragma unroll
        for (int c = 0; c < D; ++c) {
            const float a = rl(xv, c);
            aV = fmaf(a, wv[c], aV);
            aS = fmaf(a, ws[c], aS);
        }
        vx[(size_t)n * D + lane]  = aV;
        out[(size_t)n * D + lane] = aS;
    }
}

// Edge kernel: one wave per edge (grid-stride).
// gate_in = kx[dst] + qx[src] + ea@(WkE+WqE)   (biases folded into kx,qx)
// msg = sigmoid(gate_in) * (vx[src] + ea@WvE)
// out[dst] += msg  (atomic)
__global__ __launch_bounds__(256, 4)
void edge_kernel(const int* __restrict__ srcI, const int* __restrict__ dstI,
                 const float* __restrict__ ea,
                 const float* __restrict__ Wk, const float* __restrict__ Wq,
                 const float* __restrict__ Wv,
                 const float* __restrict__ kx, const float* __restrict__ qx,
                 const float* __restrict__ vx,
                 float* __restrict__ out, int nWaves) {
    const int lane = threadIdx.x & 63;
    const int wid  = blockIdx.x * 4 + (threadIdx.x >> 6);
    float wgE[ED], wvE[ED];
#pragma unroll
    for (int c = 0; c < ED; ++c) {
        // gate weight = sum of key+query edge parts (sigmoid only sees the sum)
        wgE[c] = Wk[(D + c) * D + lane] + Wq[(D + c) * D + lane];
        wvE[c] = Wv[(D + c) * D + lane];
    }
    for (int e = wid; e < EE; e += nWaves) {
        const int eu = __builtin_amdgcn_readfirstlane(e);   // wave-uniform -> scalar loads
        const int s  = srcI[eu];
        const int dd = dstI[eu];
        const float eav = ea[(size_t)eu * ED + (lane & 31)];  // coalesced, 2-way bcast
        float aG = 0.f, aV = 0.f;
#pragma unroll
        for (int c = 0; c < ED; ++c) {
            const float a = rl(eav, c);
            aG = fmaf(a, wgE[c], aG);
            aV = fmaf(a, wvE[c], aV);
        }
        const float z = kx[(size_t)dd * D + lane] + qx[(size_t)s * D + lane] + aG;
        const float v = vx[(size_t)s * D + lane] + aV;
        const float g = 1.0f / (1.0f + __expf(-z));
        unsafeAtomicAdd(&out[(size_t)dd * D + lane], g * v);
    }
}

extern "C" void kernel_launch(void* const* d_in, const int* in_sizes, int n_in,
                              void* d_out, int out_size, void* d_ws, size_t ws_size,
                              hipStream_t stream) {
    const float* x    = (const float*)d_in[0];
    const int*   eidx = (const int*)d_in[1];      // [2, E]: row0=src, row1=dst
    const float* eatt = (const float*)d_in[2];
    const float* Wk   = (const float*)d_in[3];
    const float* bk   = (const float*)d_in[4];
    const float* Wq   = (const float*)d_in[5];
    const float* bq   = (const float*)d_in[6];
    const float* Wv   = (const float*)d_in[7];
    const float* bv   = (const float*)d_in[8];
    const float* Ws   = (const float*)d_in[9];
    const float* bias = (const float*)d_in[10];
    float* out = (float*)d_out;

    float* kx = (float*)d_ws;                       // [N, D]
    float* qx = kx + (size_t)NN * D;                // [N, D]
    float* vx = qx + (size_t)NN * D;                // [N, D]

    const int* srcI = eidx;
    const int* dstI = eidx + EE;

    const int nodeBlocks = 512;
    const int nodeWaves  = nodeBlocks * 4;
    node_kq<<<nodeBlocks, 256, 0, stream>>>(x, Wk, bk, Wq, bq, kx, qx, nodeWaves);
    node_vs<<<nodeBlocks, 256, 0, stream>>>(x, Wv, bv, Ws, bias, vx, out, nodeWaves);

    const int edgeBlocks = 2048;
    const int edgeWaves  = edgeBlocks * 4;
    edge_kernel<<<edgeBlocks, 256, 0, stream>>>(srcI, dstI, eatt, Wk, Wq, Wv,
                                                kx, qx, vx, out, edgeWaves);
}

// Round 3
// 246.532 us; speedup vs baseline: 1.4746x; 1.1611x over previous
//
#include <hip/hip_runtime.h>
#include <hip/hip_bf16.h>

#define D 64
#define ED 32
#define NN 50000
#define EE 800000
#define NTILES (EE / 64)   // 12500 64-edge tiles, exact

typedef __attribute__((ext_vector_type(8))) short bf16x8;
typedef __attribute__((ext_vector_type(4))) float f32x4;
typedef __attribute__((ext_vector_type(4))) int int4v;

__device__ __forceinline__ short f2bf(float f) {
    __hip_bfloat16 h = __float2bfloat16(f);
    return *reinterpret_cast<short*>(&h);
}

// broadcast value from lane `l` (compile-time const after unroll) -> SGPR
__device__ __forceinline__ float rl(float v, int l) {
    return __int_as_float(__builtin_amdgcn_readlane(__float_as_int(v), l));
}

// Node kernel A: kx = x@Wk[:D] + bk ; qx = x@Wq[:D] + bq
__global__ __launch_bounds__(256, 3)
void node_kq(const float* __restrict__ x,
             const float* __restrict__ Wk, const float* __restrict__ bk,
             const float* __restrict__ Wq, const float* __restrict__ bq,
             float* __restrict__ kx, float* __restrict__ qx, int nWaves) {
    const int lane = threadIdx.x & 63;
    const int wid  = blockIdx.x * 4 + (threadIdx.x >> 6);
    float wk[D], wq[D];
#pragma unroll
    for (int c = 0; c < D; ++c) {
        wk[c] = Wk[c * D + lane];
        wq[c] = Wq[c * D + lane];
    }
    const float bkv = bk[lane], bqv = bq[lane];
    for (int n = wid; n < NN; n += nWaves) {
        const float xv = x[(size_t)n * D + lane];
        float aK = bkv, aQ = bqv;
#pragma unroll
        for (int c = 0; c < D; ++c) {
            const float a = rl(xv, c);
            aK = fmaf(a, wk[c], aK);
            aQ = fmaf(a, wq[c], aQ);
        }
        kx[(size_t)n * D + lane] = aK;
        qx[(size_t)n * D + lane] = aQ;
    }
}

// Node kernel B: vx = x@Wv[:D] + bv ; out = x@Wskip + bias  (initializes out)
__global__ __launch_bounds__(256, 3)
void node_vs(const float* __restrict__ x,
             const float* __restrict__ Wv, const float* __restrict__ bv,
             const float* __restrict__ Ws, const float* __restrict__ bias,
             float* __restrict__ vx, float* __restrict__ out, int nWaves) {
    const int lane = threadIdx.x & 63;
    const int wid  = blockIdx.x * 4 + (threadIdx.x >> 6);
    float wv[D], ws[D];
#pragma unroll
    for (int c = 0; c < D; ++c) {
        wv[c] = Wv[c * D + lane];
        ws[c] = Ws[c * D + lane];
    }
    const float bvv = bv[lane], bsv = bias[lane];
    for (int n = wid; n < NN; n += nWaves) {
        const float xv = x[(size_t)n * D + lane];
        float aV = bvv, aS = bsv;
#pragma unroll
        for (int c = 0; c < D; ++c) {
            const float a = rl(xv, c);
            aV = fmaf(a, wv[c], aV);
            aS = fmaf(a, ws[c], aS);
        }
        vx[(size_t)n * D + lane]  = aV;
        out[(size_t)n * D + lane] = aS;
    }
}

// Edge kernel (MFMA): per 64-edge tile per wave.
//   gate GEMM: ea[64x32] @ (WkE+WqE)[32x64]  via 16x16x32 bf16 MFMA
//   value GEMM: ea[64x32] @ WvE[32x64]
//   epilogue: z = gate + kx[dst][c] + qx[src][c]; msg = sigmoid(z)*(val + vx[src][c])
//             atomicAdd(out[dst][c], msg)
// Fragment layouts (m89-verified): A lane l -> row l&15, k 8*(l>>4)+e;
// B lane l -> col l&15, k 8*(l>>4)+e; C/D lane l -> col l&15, row (l>>4)*4+reg.
__global__ __launch_bounds__(256, 4)
void edge_mfma(const int* __restrict__ srcI, const int* __restrict__ dstI,
               const float* __restrict__ ea,
               const float* __restrict__ Wk, const float* __restrict__ Wq,
               const float* __restrict__ Wv,
               const float* __restrict__ kx, const float* __restrict__ qx,
               const float* __restrict__ vx,
               float* __restrict__ out, int nWaves) {
    const int lane = threadIdx.x & 63;
    const int wid  = blockIdx.x * 4 + (threadIdx.x >> 6);
    const int lg   = lane >> 4;     // k-block (A,B) / row-group (C)
    const int lr   = lane & 15;     // row (A) / col (B, C)

    // B-fragments, loaded once per wave: gate = WkE+WqE (sigmoid sees only the
    // sum), value = WvE. Feeding MFMA operands directly defeats remat.
    bf16x8 bg[4], bv[4];
#pragma unroll
    for (int h = 0; h < 4; ++h) {
        bf16x8 g, v;
#pragma unroll
        for (int e = 0; e < 8; ++e) {
            const int k = 8 * lg + e;
            const int col = 16 * h + lr;
            const size_t off = (size_t)(D + k) * D + col;   // edge rows of W
            g[e] = f2bf(Wk[off] + Wq[off]);
            v[e] = f2bf(Wv[off]);
        }
        bg[h] = g; bv[h] = v;
    }

    for (int t = wid; t < NTILES; t += nWaves) {
        const int e0 = t * 64;
#pragma unroll 1
        for (int g = 0; g < 4; ++g) {           // 4 edge-groups of 16
            const int ebase = e0 + 16 * g;
            // A-frag: lane holds ea[ebase + lr][8*lg .. +7], 32B contiguous
            const float* ap = ea + (size_t)(ebase + lr) * ED + 8 * lg;
            const f32x4 a0 = *(const f32x4*)ap;
            const f32x4 a1 = *(const f32x4*)(ap + 4);
            bf16x8 af;
#pragma unroll
            for (int e = 0; e < 4; ++e) { af[e] = f2bf(a0[e]); af[e + 4] = f2bf(a1[e]); }

            f32x4 accG[4], accV[4];
#pragma unroll
            for (int h = 0; h < 4; ++h) {
                accG[h] = __builtin_amdgcn_mfma_f32_16x16x32_bf16(af, bg[h], (f32x4)(0.f), 0, 0, 0);
                accV[h] = __builtin_amdgcn_mfma_f32_16x16x32_bf16(af, bv[h], (f32x4)(0.f), 0, 0, 0);
            }

            // this lane's 4 C-rows are edges ebase + lg*4 + 0..3 (16B int4 loads,
            // 16-lane broadcast within each row-group)
            const int4v sv = *(const int4v*)(srcI + ebase + 4 * lg);
            const int4v dv = *(const int4v*)(dstI + ebase + 4 * lg);
#pragma unroll
            for (int r = 0; r < 4; ++r) {
                const int s  = sv[r];
                const int dd = dv[r];
                const float* kxp = kx + (size_t)dd * D;
                const float* qxp = qx + (size_t)s * D;
                const float* vxp = vx + (size_t)s * D;
                float* outp = out + (size_t)dd * D;
#pragma unroll
                for (int h = 0; h < 4; ++h) {
                    const int c = 16 * h + lr;          // lanes 0-15: 64B coalesced
                    const float z   = accG[h][r] + kxp[c] + qxp[c];
                    const float vv  = accV[h][r] + vxp[c];
                    const float msg = __builtin_amdgcn_rcpf(1.0f + __expf(-z)) * vv;
                    unsafeAtomicAdd(&outp[c], msg);
                }
            }
        }
    }
}

extern "C" void kernel_launch(void* const* d_in, const int* in_sizes, int n_in,
                              void* d_out, int out_size, void* d_ws, size_t ws_size,
                              hipStream_t stream) {
    const float* x    = (const float*)d_in[0];
    const int*   eidx = (const int*)d_in[1];      // [2, E]: row0=src, row1=dst
    const float* eatt = (const float*)d_in[2];
    const float* Wk   = (const float*)d_in[3];
    const float* bk   = (const float*)d_in[4];
    const float* Wq   = (const float*)d_in[5];
    const float* bq   = (const float*)d_in[6];
    const float* Wv   = (const float*)d_in[7];
    const float* bv   = (const float*)d_in[8];
    const float* Ws   = (const float*)d_in[9];
    const float* bias = (const float*)d_in[10];
    float* out = (float*)d_out;

    float* kx = (float*)d_ws;                       // [N, D]
    float* qx = kx + (size_t)NN * D;                // [N, D]
    float* vx = qx + (size_t)NN * D;                // [N, D]

    const int* srcI = eidx;
    const int* dstI = eidx + EE;

    const int nodeBlocks = 512;
    const int nodeWaves  = nodeBlocks * 4;
    node_kq<<<nodeBlocks, 256, 0, stream>>>(x, Wk, bk, Wq, bq, kx, qx, nodeWaves);
    node_vs<<<nodeBlocks, 256, 0, stream>>>(x, Wv, bv, Ws, bias, vx, out, nodeWaves);

    // 12500 tiles over 4096 waves -> ~3 tiles/wave (amortizes B-frag init)
    const int edgeBlocks = 1024;
    const int edgeWaves  = edgeBlocks * 4;
    edge_mfma<<<edgeBlocks, 256, 0, stream>>>(srcI, dstI, eatt, Wk, Wq, Wv,
                                              kx, qx, vx, out, edgeWaves);
}

// Round 4
// 243.114 us; speedup vs baseline: 1.4953x; 1.0141x over previous
//
#include <hip/hip_runtime.h>
#include <hip/hip_bf16.h>

#define D 64
#define ED 32
#define NN 50000
#define EE 800000
#define NTILES (EE / 64)   // 12500 64-edge tiles, exact

typedef __attribute__((ext_vector_type(8))) short bf16x8;
typedef __attribute__((ext_vector_type(4))) float f32x4;
typedef __attribute__((ext_vector_type(4))) int int4v;

__device__ __forceinline__ short f2bf(float f) {
    __hip_bfloat16 h = __float2bfloat16(f);
    return *reinterpret_cast<short*>(&h);
}

// broadcast value from lane `l` (compile-time const after unroll) -> SGPR
__device__ __forceinline__ float rl(float v, int l) {
    return __int_as_float(__builtin_amdgcn_readlane(__float_as_int(v), l));
}

// Pre-pack edge-weight B-fragments, transposed so a lane's 8 k-values are
// contiguous: WgT[c][k] = bf16(WkE[k][c]+WqE[k][c]), WvT[c][k] = bf16(WvE[k][c]).
__global__ void prep_wfrag(const float* __restrict__ Wk, const float* __restrict__ Wq,
                           const float* __restrict__ Wv,
                           unsigned short* __restrict__ WgT, unsigned short* __restrict__ WvT) {
    const int i = blockIdx.x * 256 + threadIdx.x;   // over 64*32
    if (i < D * ED) {
        const int c = i >> 5, k = i & 31;
        const size_t off = (size_t)(D + k) * D + c;
        WgT[i] = (unsigned short)f2bf(Wk[off] + Wq[off]);
        WvT[i] = (unsigned short)f2bf(Wv[off]);
    }
}

// Node kernel A: kx = x@Wk[:D] + bk ; qx = x@Wq[:D] + bq
__global__ __launch_bounds__(256, 3)
void node_kq(const float* __restrict__ x,
             const float* __restrict__ Wk, const float* __restrict__ bk,
             const float* __restrict__ Wq, const float* __restrict__ bq,
             float* __restrict__ kx, float* __restrict__ qx, int nWaves) {
    const int lane = threadIdx.x & 63;
    const int wid  = blockIdx.x * 4 + (threadIdx.x >> 6);
    float wk[D], wq[D];
#pragma unroll
    for (int c = 0; c < D; ++c) {
        wk[c] = Wk[c * D + lane];
        wq[c] = Wq[c * D + lane];
    }
    const float bkv = bk[lane], bqv = bq[lane];
    for (int n = wid; n < NN; n += nWaves) {
        const float xv = x[(size_t)n * D + lane];
        float aK = bkv, aQ = bqv;
#pragma unroll
        for (int c = 0; c < D; ++c) {
            const float a = rl(xv, c);
            aK = fmaf(a, wk[c], aK);
            aQ = fmaf(a, wq[c], aQ);
        }
        kx[(size_t)n * D + lane] = aK;
        qx[(size_t)n * D + lane] = aQ;
    }
}

// Node kernel B: vx = x@Wv[:D] + bv ; out = x@Wskip + bias  (initializes out)
__global__ __launch_bounds__(256, 3)
void node_vs(const float* __restrict__ x,
             const float* __restrict__ Wv, const float* __restrict__ bv,
             const float* __restrict__ Ws, const float* __restrict__ bias,
             float* __restrict__ vx, float* __restrict__ out, int nWaves) {
    const int lane = threadIdx.x & 63;
    const int wid  = blockIdx.x * 4 + (threadIdx.x >> 6);
    float wv[D], ws[D];
#pragma unroll
    for (int c = 0; c < D; ++c) {
        wv[c] = Wv[c * D + lane];
        ws[c] = Ws[c * D + lane];
    }
    const float bvv = bv[lane], bsv = bias[lane];
    for (int n = wid; n < NN; n += nWaves) {
        const float xv = x[(size_t)n * D + lane];
        float aV = bvv, aS = bsv;
#pragma unroll
        for (int c = 0; c < D; ++c) {
            const float a = rl(xv, c);
            aV = fmaf(a, wv[c], aV);
            aS = fmaf(a, ws[c], aS);
        }
        vx[(size_t)n * D + lane]  = aV;
        out[(size_t)n * D + lane] = aS;
    }
}

// Edge kernel: ONE 64-edge tile per wave.
// gate = ea@(WkE+WqE), val = ea@WvE via 16x16x32 bf16 MFMA; epilogue gathers
// kx[dst],qx[src],vx[src] (hoisted into arrays for MLP), sigmoid-gate, atomic
// scatter into out[dst].
__global__ __launch_bounds__(256, 3)
void edge_mfma(const int* __restrict__ srcI, const int* __restrict__ dstI,
               const float* __restrict__ ea,
               const unsigned short* __restrict__ WgT, const unsigned short* __restrict__ WvT,
               const float* __restrict__ kx, const float* __restrict__ qx,
               const float* __restrict__ vx,
               float* __restrict__ out) {
    const int lane = threadIdx.x & 63;
    const int wid  = blockIdx.x * 4 + (threadIdx.x >> 6);
    if (wid >= NTILES) return;                 // grid is exact; safety only
    const int lg = lane >> 4;                  // k-block (A,B) / row-group (C)
    const int lr = lane & 15;                  // row (A) / col (B, C)

    // B-fragments: 8x 16B loads (hot in L2 after first tiles)
    bf16x8 bg[4], bvf[4];
#pragma unroll
    for (int h = 0; h < 4; ++h) {
        bg[h]  = *(const bf16x8*)(WgT + (size_t)(16 * h + lr) * ED + 8 * lg);
        bvf[h] = *(const bf16x8*)(WvT + (size_t)(16 * h + lr) * ED + 8 * lg);
    }

    const int e0 = wid * 64;
#pragma unroll
    for (int g = 0; g < 4; ++g) {
        const int ebase = e0 + 16 * g;
        // edge indices: 16B per row-group, NT (streamed once)
        const int4v sv = __builtin_nontemporal_load((const int4v*)(srcI + ebase + 4 * lg));
        const int4v dv = __builtin_nontemporal_load((const int4v*)(dstI + ebase + 4 * lg));
        // A-frag source: 32B contiguous per lane, NT (streamed once)
        const float* ap = ea + (size_t)(ebase + lr) * ED + 8 * lg;
        const f32x4 a0 = __builtin_nontemporal_load((const f32x4*)ap);
        const f32x4 a1 = __builtin_nontemporal_load((const f32x4*)(ap + 4));

        // hoisted gathers: 48 independent loads in flight (the latency lever)
        float kk[4][4], qk[4][4], vk[4][4];
#pragma unroll
        for (int r = 0; r < 4; ++r) {
            const float* kxp = kx + (size_t)dv[r] * D;
            const float* qxp = qx + (size_t)sv[r] * D;
            const float* vxp = vx + (size_t)sv[r] * D;
#pragma unroll
            for (int h = 0; h < 4; ++h) {
                const int c = 16 * h + lr;
                kk[r][h] = kxp[c];
                qk[r][h] = qxp[c];
                vk[r][h] = vxp[c];
            }
        }

        bf16x8 af;
#pragma unroll
        for (int e = 0; e < 4; ++e) { af[e] = f2bf(a0[e]); af[e + 4] = f2bf(a1[e]); }

        f32x4 accG[4], accV[4];
#pragma unroll
        for (int h = 0; h < 4; ++h) {
            accG[h] = __builtin_amdgcn_mfma_f32_16x16x32_bf16(af, bg[h],  (f32x4)(0.f), 0, 0, 0);
            accV[h] = __builtin_amdgcn_mfma_f32_16x16x32_bf16(af, bvf[h], (f32x4)(0.f), 0, 0, 0);
        }

#pragma unroll
        for (int r = 0; r < 4; ++r) {
            float* outp = out + (size_t)dv[r] * D;
#pragma unroll
            for (int h = 0; h < 4; ++h) {
                const int c   = 16 * h + lr;
                const float z = accG[h][r] + kk[r][h] + qk[r][h];
                const float v = accV[h][r] + vk[r][h];
                const float msg = v * __builtin_amdgcn_rcpf(1.0f + __expf(-z));
                unsafeAtomicAdd(&outp[c], msg);
            }
        }
    }
}

extern "C" void kernel_launch(void* const* d_in, const int* in_sizes, int n_in,
                              void* d_out, int out_size, void* d_ws, size_t ws_size,
                              hipStream_t stream) {
    const float* x    = (const float*)d_in[0];
    const int*   eidx = (const int*)d_in[1];      // [2, E]: row0=src, row1=dst
    const float* eatt = (const float*)d_in[2];
    const float* Wk   = (const float*)d_in[3];
    const float* bk   = (const float*)d_in[4];
    const float* Wq   = (const float*)d_in[5];
    const float* bq   = (const float*)d_in[6];
    const float* Wv   = (const float*)d_in[7];
    const float* bv   = (const float*)d_in[8];
    const float* Ws   = (const float*)d_in[9];
    const float* bias = (const float*)d_in[10];
    float* out = (float*)d_out;

    float* kx = (float*)d_ws;                       // [N, D]
    float* qx = kx + (size_t)NN * D;                // [N, D]
    float* vx = qx + (size_t)NN * D;                // [N, D]
    unsigned short* WgT = (unsigned short*)(vx + (size_t)NN * D);  // [64][32] bf16
    unsigned short* WvT = WgT + D * ED;                             // [64][32] bf16

    const int* srcI = eidx;
    const int* dstI = eidx + EE;

    prep_wfrag<<<(D * ED + 255) / 256, 256, 0, stream>>>(Wk, Wq, Wv, WgT, WvT);

    const int nodeBlocks = 512;
    const int nodeWaves  = nodeBlocks * 4;
    node_kq<<<nodeBlocks, 256, 0, stream>>>(x, Wk, bk, Wq, bq, kx, qx, nodeWaves);
    node_vs<<<nodeBlocks, 256, 0, stream>>>(x, Wv, bv, Ws, bias, vx, out, nodeWaves);

    // one tile per wave: 12500 waves = 3125 blocks
    edge_mfma<<<NTILES / 4, 256, 0, stream>>>(srcI, dstI, eatt, WgT, WvT,
                                              kx, qx, vx, out);
}

// Round 5
// 234.633 us; speedup vs baseline: 1.5494x; 1.0361x over previous
//
#include <hip/hip_runtime.h>
#include <hip/hip_bf16.h>

#define D 64
#define ED 32
#define NN 50000
#define EE 800000
#define NT32 (EE / 32)   // 25000 32-edge tiles, exact

typedef __attribute__((ext_vector_type(8))) short bf16x8;
typedef __attribute__((ext_vector_type(4))) float f32x4;
typedef __attribute__((ext_vector_type(4))) int int4v;

__device__ __forceinline__ short f2bf(float f) {
    __hip_bfloat16 h = __float2bfloat16(f);
    return *reinterpret_cast<short*>(&h);
}
__device__ __forceinline__ float bfhi2f(unsigned w) {          // high 16 bits as bf16
    return __uint_as_float(w & 0xFFFF0000u);
}
__device__ __forceinline__ float bflo2f(unsigned w) {          // low 16 bits as bf16
    return __uint_as_float(w << 16);
}
__device__ __forceinline__ unsigned packqv(float q, float v) {
    return (unsigned)(unsigned short)f2bf(q) | ((unsigned)(unsigned short)f2bf(v) << 16);
}

// broadcast value from lane `l` (compile-time const after unroll) -> SGPR
__device__ __forceinline__ float rl(float v, int l) {
    return __int_as_float(__builtin_amdgcn_readlane(__float_as_int(v), l));
}

// Pre-pack edge-weight B-fragments, transposed: WgT[c][k]=bf16(WkE+WqE), WvT[c][k]=bf16(WvE)
__global__ void prep_wfrag(const float* __restrict__ Wk, const float* __restrict__ Wq,
                           const float* __restrict__ Wv,
                           unsigned short* __restrict__ WgT, unsigned short* __restrict__ WvT) {
    const int i = blockIdx.x * 256 + threadIdx.x;   // over 64*32
    if (i < D * ED) {
        const int c = i >> 5, k = i & 31;
        const size_t off = (size_t)(D + k) * D + c;
        WgT[i] = (unsigned short)f2bf(Wk[off] + Wq[off]);
        WvT[i] = (unsigned short)f2bf(Wv[off]);
    }
}

// Node kernel A: kx = x@Wk[:D] + bk (f32) ; out = x@Wskip + bias (initializes out)
__global__ __launch_bounds__(256, 3)
void node_ks(const float* __restrict__ x,
             const float* __restrict__ Wk, const float* __restrict__ bk,
             const float* __restrict__ Ws, const float* __restrict__ bias,
             float* __restrict__ kx, float* __restrict__ out, int nWaves) {
    const int lane = threadIdx.x & 63;
    const int wid  = blockIdx.x * 4 + (threadIdx.x >> 6);
    float wk[D], ws[D];
#pragma unroll
    for (int c = 0; c < D; ++c) {
        wk[c] = Wk[c * D + lane];
        ws[c] = Ws[c * D + lane];
    }
    const float bkv = bk[lane], bsv = bias[lane];
    for (int n = wid; n < NN; n += nWaves) {
        const float xv = x[(size_t)n * D + lane];
        float aK = bkv, aS = bsv;
#pragma unroll
        for (int c = 0; c < D; ++c) {
            const float a = rl(xv, c);
            aK = fmaf(a, wk[c], aK);
            aS = fmaf(a, ws[c], aS);
        }
        kx[(size_t)n * D + lane]  = aK;
        out[(size_t)n * D + lane] = aS;
    }
}

// Node kernel B: qv[n][c] = pack(bf16(x@Wq+bq), bf16(x@Wv+bv))
__global__ __launch_bounds__(256, 3)
void node_qv(const float* __restrict__ x,
             const float* __restrict__ Wq, const float* __restrict__ bq,
             const float* __restrict__ Wv, const float* __restrict__ bv,
             unsigned* __restrict__ qv, int nWaves) {
    const int lane = threadIdx.x & 63;
    const int wid  = blockIdx.x * 4 + (threadIdx.x >> 6);
    float wq[D], wv[D];
#pragma unroll
    for (int c = 0; c < D; ++c) {
        wq[c] = Wq[c * D + lane];
        wv[c] = Wv[c * D + lane];
    }
    const float bqv = bq[lane], bvv = bv[lane];
    for (int n = wid; n < NN; n += nWaves) {
        const float xv = x[(size_t)n * D + lane];
        float aQ = bqv, aV = bvv;
#pragma unroll
        for (int c = 0; c < D; ++c) {
            const float a = rl(xv, c);
            aQ = fmaf(a, wq[c], aQ);
            aV = fmaf(a, wv[c], aV);
        }
        qv[(size_t)n * D + lane] = packqv(aQ, aV);
    }
}

// Edge kernel: 32 edges (2 MFMA groups) per wave; all loads hoisted for MLP.
__global__ __launch_bounds__(256, 3)
void edge_mfma(const int* __restrict__ srcI, const int* __restrict__ dstI,
               const float* __restrict__ ea,
               const unsigned short* __restrict__ WgT, const unsigned short* __restrict__ WvT,
               const float* __restrict__ kx, const unsigned* __restrict__ qv,
               float* __restrict__ out) {
    const int lane = threadIdx.x & 63;
    const int wid  = blockIdx.x * 4 + (threadIdx.x >> 6);
    if (wid >= NT32) return;
    const int lg = lane >> 4;                  // k-block (A,B) / row-group (C)
    const int lr = lane & 15;                  // row (A) / col (B, C)
    const int e0 = wid * 32;

    // 1) edge indices first — longest dependency chain (gathers hang off them)
    const int4v sv0 = __builtin_nontemporal_load((const int4v*)(srcI + e0 + 4 * lg));
    const int4v dv0 = __builtin_nontemporal_load((const int4v*)(dstI + e0 + 4 * lg));
    const int4v sv1 = __builtin_nontemporal_load((const int4v*)(srcI + e0 + 16 + 4 * lg));
    const int4v dv1 = __builtin_nontemporal_load((const int4v*)(dstI + e0 + 16 + 4 * lg));

    // 2) A-operand rows (streamed once)
    const float* ap0 = ea + (size_t)(e0 + lr) * ED + 8 * lg;
    const float* ap1 = ea + (size_t)(e0 + 16 + lr) * ED + 8 * lg;
    const f32x4 a00 = __builtin_nontemporal_load((const f32x4*)ap0);
    const f32x4 a01 = __builtin_nontemporal_load((const f32x4*)(ap0 + 4));
    const f32x4 a10 = __builtin_nontemporal_load((const f32x4*)ap1);
    const f32x4 a11 = __builtin_nontemporal_load((const f32x4*)(ap1 + 4));

    // 3) B-fragments (L2-hot)
    bf16x8 bg[4], bvf[4];
#pragma unroll
    for (int h = 0; h < 4; ++h) {
        bg[h]  = *(const bf16x8*)(WgT + (size_t)(16 * h + lr) * ED + 8 * lg);
        bvf[h] = *(const bf16x8*)(WvT + (size_t)(16 * h + lr) * ED + 8 * lg);
    }

    // 4) all gathers hoisted: 32 f32 (kx[dst]) + 32 uint (qv[src]) in flight
    float    kk[2][4][4];
    unsigned qw[2][4][4];
#pragma unroll
    for (int r = 0; r < 4; ++r) {
        const float*    kp0 = kx + (size_t)dv0[r] * D;
        const unsigned* qp0 = qv + (size_t)sv0[r] * D;
        const float*    kp1 = kx + (size_t)dv1[r] * D;
        const unsigned* qp1 = qv + (size_t)sv1[r] * D;
#pragma unroll
        for (int h = 0; h < 4; ++h) {
            const int c = 16 * h + lr;
            kk[0][r][h] = kp0[c];
            qw[0][r][h] = qp0[c];
            kk[1][r][h] = kp1[c];
            qw[1][r][h] = qp1[c];
        }
    }

    // 5) A fragments (bf16 convert)
    bf16x8 af0, af1;
#pragma unroll
    for (int e = 0; e < 4; ++e) {
        af0[e] = f2bf(a00[e]); af0[e + 4] = f2bf(a01[e]);
        af1[e] = f2bf(a10[e]); af1[e + 4] = f2bf(a11[e]);
    }

    // 6) MFMAs
    f32x4 accG0[4], accV0[4], accG1[4], accV1[4];
#pragma unroll
    for (int h = 0; h < 4; ++h) {
        accG0[h] = __builtin_amdgcn_mfma_f32_16x16x32_bf16(af0, bg[h],  (f32x4)(0.f), 0, 0, 0);
        accV0[h] = __builtin_amdgcn_mfma_f32_16x16x32_bf16(af0, bvf[h], (f32x4)(0.f), 0, 0, 0);
        accG1[h] = __builtin_amdgcn_mfma_f32_16x16x32_bf16(af1, bg[h],  (f32x4)(0.f), 0, 0, 0);
        accV1[h] = __builtin_amdgcn_mfma_f32_16x16x32_bf16(af1, bvf[h], (f32x4)(0.f), 0, 0, 0);
    }

    // 7) epilogue: gate + atomic scatter
#pragma unroll
    for (int r = 0; r < 4; ++r) {
        float* op0 = out + (size_t)dv0[r] * D;
        float* op1 = out + (size_t)dv1[r] * D;
#pragma unroll
        for (int h = 0; h < 4; ++h) {
            const int c = 16 * h + lr;
            {
                const float z = accG0[h][r] + kk[0][r][h] + bflo2f(qw[0][r][h]);
                const float v = accV0[h][r] + bfhi2f(qw[0][r][h]);
                unsafeAtomicAdd(&op0[c], v * __builtin_amdgcn_rcpf(1.0f + __expf(-z)));
            }
            {
                const float z = accG1[h][r] + kk[1][r][h] + bflo2f(qw[1][r][h]);
                const float v = accV1[h][r] + bfhi2f(qw[1][r][h]);
                unsafeAtomicAdd(&op1[c], v * __builtin_amdgcn_rcpf(1.0f + __expf(-z)));
            }
        }
    }
}

extern "C" void kernel_launch(void* const* d_in, const int* in_sizes, int n_in,
                              void* d_out, int out_size, void* d_ws, size_t ws_size,
                              hipStream_t stream) {
    const float* x    = (const float*)d_in[0];
    const int*   eidx = (const int*)d_in[1];      // [2, E]: row0=src, row1=dst
    const float* eatt = (const float*)d_in[2];
    const float* Wk   = (const float*)d_in[3];
    const float* bk   = (const float*)d_in[4];
    const float* Wq   = (const float*)d_in[5];
    const float* bq   = (const float*)d_in[6];
    const float* Wv   = (const float*)d_in[7];
    const float* bv   = (const float*)d_in[8];
    const float* Ws   = (const float*)d_in[9];
    const float* bias = (const float*)d_in[10];
    float* out = (float*)d_out;

    float*    kx = (float*)d_ws;                        // [N, D] f32
    unsigned* qv = (unsigned*)(kx + (size_t)NN * D);    // [N, D] packed bf16x2
    unsigned short* WgT = (unsigned short*)(qv + (size_t)NN * D);  // [64][32] bf16
    unsigned short* WvT = WgT + D * ED;

    const int* srcI = eidx;
    const int* dstI = eidx + EE;

    prep_wfrag<<<(D * ED + 255) / 256, 256, 0, stream>>>(Wk, Wq, Wv, WgT, WvT);

    const int nodeBlocks = 512;
    const int nodeWaves  = nodeBlocks * 4;
    node_ks<<<nodeBlocks, 256, 0, stream>>>(x, Wk, bk, Ws, bias, kx, out, nodeWaves);
    node_qv<<<nodeBlocks, 256, 0, stream>>>(x, Wq, bq, Wv, bv, qv, nodeWaves);

    // one 32-edge tile per wave: 25000 waves = 6250 blocks
    edge_mfma<<<NT32 / 4, 256, 0, stream>>>(srcI, dstI, eatt, WgT, WvT, kx, qv, out);
}